// Round 11
// baseline (76.296 us; speedup 1.0000x reference)
//
#include <hip/hip_runtime.h>

// LocalConv ablation round: r4 structure (best, 37.6us) instrumented as
// template<MODE>: 0=full, 1=staging-only (no frag reads/MFMA/stores),
// 2=compute-only (no A staging, no weight pipeline). P1,P2 -> d_out scratch
// region (overwritten), real FULL kernel launched last produces d_out.
#define CIN    16
#define HH     64
#define WW     64
#define OHD    62
#define OWD    62
#define OUTC   32
#define FEATN  144
#define POUT   (OHD*OWD)
#define LSTRB  152
#define AR_W   10
#define AR_ELEMS   (3*AR_W*64*16)       // 30720
#define BBUF_ELEMS (OUTC*LSTRB + 8)     // 4872
#define SMEM_BYTES ((AR_ELEMS + 2*BBUF_ELEMS)*2)   // 80928

typedef __attribute__((ext_vector_type(8))) short  short8;
typedef __attribute__((ext_vector_type(4))) float  f32x4;
typedef __attribute__((ext_vector_type(2))) float  f32x2;

__device__ __forceinline__ unsigned short f2bf(float f) {
    unsigned int u = __float_as_uint(f);
    u += 0x7FFFu + ((u >> 16) & 1u);   // RNE
    return (unsigned short)(u >> 16);
}

template<int TW, int MODE>
__device__ __forceinline__ void conv_body(
    const float* __restrict__ inp, const float* __restrict__ wgt,
    float* __restrict__ out, int oh, int ow0,
    unsigned short* __restrict__ Araw, unsigned short* __restrict__ B_lds)
{
    const int tid = threadIdx.x;
    constexpr int WTOT = TW + 2;
    constexpr bool DO_STAGE   = (MODE != 2);
    constexpr bool DO_COMPUTE = (MODE != 1);

    if constexpr (DO_STAGE) {
        // ---- stage A slab (r4-verified swizzle)
        for (int t = tid; t < 3 * WTOT * 64; t += 512) {
            int w   = t % WTOT;
            int rem = t / WTOT;
            int b   = rem & 63;
            int kh  = rem >> 6;
            const float* src = inp + (size_t)b * (CIN * HH * WW)
                                   + (size_t)(oh + kh) * WW + (ow0 + w);
            short8 h0, h1;
            #pragma unroll
            for (int c = 0; c < 8; ++c) h0[c] = (short)f2bf(src[c * (HH * WW)]);
            #pragma unroll
            for (int c = 0; c < 8; ++c) h1[c] = (short)f2bf(src[(c + 8) * (HH * WW)]);
            int s = (b >> 2) & 1;
            unsigned Gb = (unsigned)(((kh * AR_W + w) * 64 + b) * 2);
            unsigned wx = (unsigned)((w & 3) << 1);
            *(short8*)(Araw + (((Gb + s) ^ wx) << 3))       = h0;
            *(short8*)(Araw + (((Gb + (1 - s)) ^ wx) << 3)) = h1;
        }
        // ---- zero B pad + guard
        for (int t = tid; t < 2 * 264; t += 512) {
            int buf = t / 264, r = t % 264;
            int e = (r < 256) ? ((r >> 3) * LSTRB + 144 + (r & 7))
                              : (OUTC * LSTRB + (r & 7));
            B_lds[buf * BBUF_ELEMS + e] = 0;
        }
    }

    // ---- weight pipeline (r4): gather 8 scalars -> ds_write_b128
    const int o_w   = tid & 31;
    const int g_w   = (tid >> 6);
    const int h_w   = (tid >> 5) & 1;
    const int gbase  = (h_w * 72 + g_w) * 32 + o_w;
    const int gbase2 = ((((tid >> 5) & 1) * 72 + 8) * 32) + o_w;
    const int woff   = o_w * LSTRB + g_w * 16 + h_w * 8;
    const int woff2  = o_w * LSTRB + 128 + ((tid >> 5) & 1) * 8;
    const int p0 = oh * OWD + ow0;

    float wv[8], wv2[8];
    auto issue = [&](int q) {
        const float* wp = wgt + (size_t)(p0 + q) * (FEATN * OUTC);
        #pragma unroll
        for (int j = 0; j < 8; ++j) wv[j] = wp[gbase + j * 288];
        if (tid < 64) {
            #pragma unroll
            for (int j = 0; j < 8; ++j) wv2[j] = wp[gbase2 + j * 288];
        }
    };
    auto writeB = [&](unsigned short* Bb) {
        short8 sv;
        #pragma unroll
        for (int j = 0; j < 8; ++j) sv[j] = (short)f2bf(wv[j]);
        *(short8*)(Bb + woff) = sv;
        if (tid < 64) {
            short8 sv2;
            #pragma unroll
            for (int j = 0; j < 8; ++j) sv2[j] = (short)f2bf(wv2[j]);
            *(short8*)(Bb + woff2) = sv2;
        }
    };

    if constexpr (DO_STAGE) {
        issue(0);
        writeB(B_lds);
        issue(1);
    }

    // ---- fragment addressing
    const int wid = tid >> 6, lane = tid & 63;
    const int fr = lane & 15, fq = lane >> 4, fqh = fq >> 1;
    const int mt = wid >> 1, nt = wid & 1;
    const int b  = mt * 16 + fr;
    const int gr = (fq & 1) ^ ((b >> 2) & 1);
    unsigned abase_g[5]; int kwv[5]; int boff[5];
    #pragma unroll
    for (int kc = 0; kc < 5; ++kc) {
        int g  = 2 * kc + fqh;
        int gc = (g > 8) ? 8 : g;
        int kh = (gc * 11) >> 5;
        int kw = gc - 3 * kh;
        abase_g[kc] = (unsigned)(((kh * AR_W + kw) * 64 + b) * 2 + gr);
        kwv[kc]     = kw;
        boff[kc]    = (nt * 16 + fr) * LSTRB + kc * 32 + fq * 8;
    }

    __syncthreads();

    f32x4 acc[TW];
    #pragma unroll
    for (int q = 0; q < TW; ++q) acc[q] = (f32x4){0.f, 0.f, 0.f, 0.f};

    // ---- main loop: [MFMA(q)] | [writeB(q+1)] | barrier | [issue(q+2)]
    #pragma unroll
    for (int q = 0; q < TW; ++q) {
        if constexpr (DO_COMPUTE) {
            const unsigned short* Bc = B_lds + (q & 1) * BBUF_ELEMS;
            #pragma unroll
            for (int kc = 0; kc < 5; ++kc) {
                short8 a;
                if (kc == 4 && fqh == 1) {
                    a = (short8){0, 0, 0, 0, 0, 0, 0, 0};
                } else {
                    unsigned gi = (abase_g[kc] + (unsigned)(q * 128))
                                  ^ (unsigned)(((q + kwv[kc]) & 3) << 1);
                    a = *(const short8*)(Araw + (gi << 3));
                }
                short8 bfv = *(const short8*)(Bc + boff[kc]);
                acc[q] = __builtin_amdgcn_mfma_f32_16x16x32_bf16(a, bfv, acc[q], 0, 0, 0);
            }
        }
        if constexpr (DO_STAGE) {
            if (q + 1 < TW) writeB(B_lds + ((q + 1) & 1) * BBUF_ELEMS);
        }
        __syncthreads();
        if constexpr (DO_STAGE) {
            if (q + 2 < TW) issue(q + 2);
        }
    }

    if constexpr (DO_COMPUTE) {
        // ---- epilogue (real store pattern; probes' stores overwritten later)
        const int o = nt * 16 + fr;
        #pragma unroll
        for (int r = 0; r < 4; ++r) {
            float* dst = out + ((size_t)((mt * 16 + fq * 4 + r) * OUTC + o)) * POUT
                             + (size_t)oh * OWD + ow0;
            #pragma unroll
            for (int j = 0; j < TW / 2; ++j) {
                f32x2 v = { acc[2 * j][r], acc[2 * j + 1][r] };
                *(f32x2*)(dst + 2 * j) = v;
            }
        }
    } else {
        // keep-alive: read back LDS so staging isn't DCE'd (rule #17)
        float v = (float)B_lds[tid] + (float)Araw[tid];
        out[(size_t)blockIdx.x * 512 + tid] = v;   // scratch region, overwritten
    }
}

template<int MODE>
__global__ __launch_bounds__(512, 4) void localconv_kernel(
    const float* __restrict__ inp,
    const float* __restrict__ wgt,
    float* __restrict__ out)
{
    extern __shared__ unsigned short smem[];
    unsigned short* Araw  = smem;
    unsigned short* B_lds = smem + AR_ELEMS;

    const int l   = (blockIdx.x & 7) * 62 + (blockIdx.x >> 3);
    const int oh  = l >> 3;
    const int owt = l & 7;

    if (owt < 7) conv_body<8, MODE>(inp, wgt, out, oh, owt * 8, Araw, B_lds);
    else         conv_body<6, MODE>(inp, wgt, out, oh, 56, Araw, B_lds);
}

extern "C" void kernel_launch(void* const* d_in, const int* in_sizes, int n_in,
                              void* d_out, int out_size, void* d_ws, size_t ws_size,
                              hipStream_t stream) {
    const float* inp = (const float*)d_in[0];
    const float* wgt = (const float*)d_in[1];
    float* out = (float*)d_out;
    hipFuncSetAttribute((const void*)localconv_kernel<0>,
                        hipFuncAttributeMaxDynamicSharedMemorySize, SMEM_BYTES);
    hipFuncSetAttribute((const void*)localconv_kernel<1>,
                        hipFuncAttributeMaxDynamicSharedMemorySize, SMEM_BYTES);
    hipFuncSetAttribute((const void*)localconv_kernel<2>,
                        hipFuncAttributeMaxDynamicSharedMemorySize, SMEM_BYTES);
    // P1: staging-only   P2: compute-only   then the real kernel (validates)
    localconv_kernel<1><<<dim3(496), 512, SMEM_BYTES, stream>>>(inp, wgt, out);
    localconv_kernel<2><<<dim3(496), 512, SMEM_BYTES, stream>>>(inp, wgt, out);
    localconv_kernel<0><<<dim3(496), 512, SMEM_BYTES, stream>>>(inp, wgt, out);
}

// Round 12
// 42.887 us; speedup vs baseline: 1.7790x; 1.7790x over previous
//
#include <hip/hip_runtime.h>

// LocalConv: out[b][o][oh][ow] = sum_f patch[p][b][f] * W[p][f][o]
// B=64, C=16, H=W=64, K=3x3, OH=OW=62, OUT_CH=32, FEAT=144, P=3844
// Round 12: ONE-SHOT staging. All weight loads (TW=4 pos x 9/thread) and the
// A-slab issued up-front as independent loads; LDS writes gated only by
// compiler-counted vmcnt; ONE __syncthreads; then barrier-free compute.
// No per-position heartbeat. r4-verified swizzle/frag/epilogue machinery.
#define CIN    16
#define HH     64
#define WW     64
#define OHD    62
#define OWD    62
#define OUTC   32
#define FEATN  144
#define POUT   (OHD*OWD)
#define LSTRB  152                      // B row stride: 144 real + 8 zero pad
#define AR_W   6                        // A slab w-dim (TW+2 max)
#define AR_ELEMS   (3*AR_W*64*16)       // 18432 elems = 36864 B
#define BBUF_ELEMS (OUTC*LSTRB + 8)     // 4872 per position (8 = zero guard)
#define SMEM_BYTES ((AR_ELEMS + 4*BBUF_ELEMS)*2)   // 75840 B

typedef __attribute__((ext_vector_type(8))) short  short8;
typedef __attribute__((ext_vector_type(4))) float  f32x4;
typedef __attribute__((ext_vector_type(4), aligned(4))) float f32x4u;
typedef __attribute__((ext_vector_type(2), aligned(4))) float f32x2u;

__device__ __forceinline__ unsigned short f2bf(float f) {
    unsigned int u = __float_as_uint(f);
    u += 0x7FFFu + ((u >> 16) & 1u);   // RNE
    return (unsigned short)(u >> 16);
}

template<int TW>
__device__ __forceinline__ void conv_body(
    const float* __restrict__ inp, const float* __restrict__ wgt,
    float* __restrict__ out, int oh, int ow0,
    unsigned short* __restrict__ Araw, unsigned short* __restrict__ B_lds)
{
    const int tid = threadIdx.x;
    constexpr int WTOT = TW + 2;

    // ---- weight loads, ALL positions up front (balanced r6 mapping):
    //      thread = (o_w = tid&31, c_w = tid>>5); f = c_w*9 + g, 9/pos.
    //      Each wave-instr = 2 dense 128B lines. 9*TW independent loads.
    const int o_w = tid & 31;
    const int c_w = tid >> 5;
    const int p0  = oh * OWD + ow0;
    const float* wbase = wgt + (size_t)p0 * (FEATN * OUTC) + c_w * 288 + o_w;
    float wv[TW][9];
    #pragma unroll
    for (int q = 0; q < TW; ++q) {
        const float* p = wbase + (size_t)q * (FEATN * OUTC);
        #pragma unroll
        for (int g = 0; g < 9; ++g) wv[q][g] = p[g * 32];
    }

    // ---- stage A slab (r4-verified): granule G = ((kh*AR_W+w)*64+b)*2 + gr,
    //      gr = half ^ ((b>>2)&1); G ^= (w&3)<<1
    for (int t = tid; t < 3 * WTOT * 64; t += 512) {
        int w   = t % WTOT;
        int rem = t / WTOT;
        int b   = rem & 63;
        int kh  = rem >> 6;
        const float* src = inp + (size_t)b * (CIN * HH * WW)
                               + (size_t)(oh + kh) * WW + (ow0 + w);
        short8 h0, h1;
        #pragma unroll
        for (int c = 0; c < 8; ++c) h0[c] = (short)f2bf(src[c * (HH * WW)]);
        #pragma unroll
        for (int c = 0; c < 8; ++c) h1[c] = (short)f2bf(src[(c + 8) * (HH * WW)]);
        int s = (b >> 2) & 1;
        unsigned Gb = (unsigned)(((kh * AR_W + w) * 64 + b) * 2);
        unsigned wx = (unsigned)((w & 3) << 1);
        *(short8*)(Araw + (((Gb + s) ^ wx) << 3))       = h0;
        *(short8*)(Araw + (((Gb + (1 - s)) ^ wx) << 3)) = h1;
    }

    // ---- zero B pad [144,152) per row + 8-elem guard, all TW buffers
    for (int t = tid; t < TW * 264; t += 512) {
        int buf = t / 264, r = t % 264;
        int e = (r < 256) ? ((r >> 3) * LSTRB + 144 + (r & 7))
                          : (OUTC * LSTRB + (r & 7));
        B_lds[buf * BBUF_ELEMS + e] = 0;
    }

    // ---- write ALL weights to LDS (vmcnt waits are counted, no barriers)
    const int wb_base = o_w * LSTRB + c_w;     // + g*16
    #pragma unroll
    for (int q = 0; q < TW; ++q) {
        unsigned short* Bb = B_lds + q * BBUF_ELEMS;
        #pragma unroll
        for (int g = 0; g < 9; ++g)
            Bb[wb_base + g * 16] = f2bf(wv[q][g]);
    }

    // ---- fragment addressing (r4/r6-verified)
    const int wid = tid >> 6, lane = tid & 63;
    const int fr = lane & 15, fq = lane >> 4, fqh = fq >> 1;
    const int mt = wid >> 1, nt = wid & 1;           // 4 m-tiles x 2 n-tiles
    const int b  = mt * 16 + fr;
    const int gr = (fq & 1) ^ ((b >> 2) & 1);
    unsigned abase_g[5]; int kwv[5]; int boff[5];
    #pragma unroll
    for (int kc = 0; kc < 5; ++kc) {
        int g  = 2 * kc + fqh;                 // 9 -> pad (zero A-frag)
        int gc = (g > 8) ? 8 : g;
        int kh = (gc * 11) >> 5;               // gc/3
        int kw = gc - 3 * kh;
        abase_g[kc] = (unsigned)(((kh * AR_W + kw) * 64 + b) * 2 + gr);
        kwv[kc]     = kw;
        boff[kc]    = (nt * 16 + fr) * LSTRB + kc * 32 + fq * 8;
    }

    __syncthreads();   // the ONLY barrier

    f32x4 acc[TW];
    #pragma unroll
    for (int q = 0; q < TW; ++q) acc[q] = (f32x4){0.f, 0.f, 0.f, 0.f};

    // ---- barrier-free compute
    #pragma unroll
    for (int q = 0; q < TW; ++q) {
        const unsigned short* Bc = B_lds + q * BBUF_ELEMS;
        #pragma unroll
        for (int kc = 0; kc < 5; ++kc) {
            short8 a;
            if (kc == 4 && fqh == 1) {
                a = (short8){0, 0, 0, 0, 0, 0, 0, 0};   // K in [144,160): A=0
            } else {
                unsigned gi = (abase_g[kc] + (unsigned)(q * 128))
                              ^ (unsigned)(((q + kwv[kc]) & 3) << 1);
                a = *(const short8*)(Araw + (gi << 3));
            }
            short8 bfv = *(const short8*)(Bc + boff[kc]);
            acc[q] = __builtin_amdgcn_mfma_f32_16x16x32_bf16(a, bfv, acc[q], 0, 0, 0);
        }
    }

    // ---- epilogue: lane owns (b_out = mt*16+fq*4+r, o = nt*16+fr),
    //      TW consecutive floats along ow
    const int o = nt * 16 + fr;
    #pragma unroll
    for (int r = 0; r < 4; ++r) {
        float* dst = out + ((size_t)((mt * 16 + fq * 4 + r) * OUTC + o)) * POUT
                         + (size_t)oh * OWD + ow0;
        if constexpr (TW == 4) {
            f32x4u v = { acc[0][r], acc[1][r], acc[2][r], acc[3][r] };
            *(f32x4u*)dst = v;
        } else {
            f32x2u v = { acc[0][r], acc[1][r] };
            *(f32x2u*)dst = v;
        }
    }
}

__global__ __launch_bounds__(512, 2) void localconv_kernel(
    const float* __restrict__ inp,
    const float* __restrict__ wgt,
    float* __restrict__ out)
{
    extern __shared__ unsigned short smem[];
    unsigned short* Araw  = smem;
    unsigned short* B_lds = smem + AR_ELEMS;

    // chunked XCD swizzle: 992 = 8*124; XCD x gets contiguous l in [124x,124x+124)
    const int bid = blockIdx.x;
    const int l   = (bid & 7) * 124 + (bid >> 3);
    const int oh    = l >> 4;          // 0..61
    const int strip = l & 15;          // 0..15

    if (strip < 15) conv_body<4>(inp, wgt, out, oh, strip * 4, Araw, B_lds);
    else            conv_body<2>(inp, wgt, out, oh, 60, Araw, B_lds);
}

extern "C" void kernel_launch(void* const* d_in, const int* in_sizes, int n_in,
                              void* d_out, int out_size, void* d_ws, size_t ws_size,
                              hipStream_t stream) {
    const float* inp = (const float*)d_in[0];
    const float* wgt = (const float*)d_in[1];
    float* out = (float*)d_out;
    hipFuncSetAttribute((const void*)localconv_kernel,
                        hipFuncAttributeMaxDynamicSharedMemorySize, SMEM_BYTES);
    localconv_kernel<<<dim3(992), 512, SMEM_BYTES, stream>>>(inp, wgt, out);
}